// Round 13
// baseline (489.522 us; speedup 1.0000x reference)
//
#include <hip/hip_runtime.h>

// Problem constants (B,T,A,D,U) = (64, 2048, 512, 512, 512)
constexpr int U = 512;
constexpr int B = 64;
constexpr int T = 2048;
constexpr int A = 512;

typedef __attribute__((ext_vector_type(8))) short short8;   // 8 bf16 = 4 VGPRs (MFMA A/B frag)
typedef __attribute__((ext_vector_type(4))) float f32x4;    // MFMA C/D frag

__device__ __forceinline__ unsigned short f32_to_bf16(float f) {
    unsigned int b = __float_as_uint(f);
    unsigned int r = (b + 0x7FFFu + ((b >> 16) & 1u)) >> 16;
    return (unsigned short)r;
}

__device__ __forceinline__ float fast_tanh(float x) {
    float e = exp2f(x * 2.885390081777927f);
    return (e - 1.0f) * __builtin_amdgcn_rcpf(e + 1.0f);
}

__device__ __forceinline__ float hard_sigmoid(float z) {
    return fminf(fmaxf(0.2f * z + 0.5f, 0.0f), 1.0f);
}

#define SB() __builtin_amdgcn_sched_barrier(0)

// ---------------------------------------------------------------------------
// K1a: split-K partials for S = bias_u + h @ kernel_w. grid 256 x 256.
__global__ __launch_bounds__(256) void k_prep_s(const float* __restrict__ h,
                                                const float* __restrict__ kw,
                                                float* __restrict__ Sp) {
    int b = blockIdx.x >> 2;
    int kc = blockIdx.x & 3;
    int u = threadIdx.x;
    const float* hb = h + b * U + kc * 128;
    const float* kwb = kw + (size_t)kc * 128 * U;
    float a0 = 0.f, a1 = 0.f;
#pragma unroll 4
    for (int k = 0; k < 128; ++k) {
        float hv = hb[k];
        a0 += hv * kwb[(size_t)k * U + u];
        a1 += hv * kwb[(size_t)k * U + u + 256];
    }
    float* p = Sp + ((size_t)kc * 64 + b) * U;
    p[u] = a0;
    p[u + 256] = a1;
}

// K1a2: S[b][u] = bias_u[u] + sum_kc Sp. grid 128 x 256
__global__ __launch_bounds__(256) void k_s_reduce(const float* __restrict__ Sp,
                                                  const float* __restrict__ bias,
                                                  float* __restrict__ S) {
    int gid = blockIdx.x * 256 + threadIdx.x;
    int b = gid >> 9, u = gid & 511;
    float s = bias[4 * U + u];
#pragma unroll
    for (int kc = 0; kc < 4; ++kc) s += Sp[((size_t)kc * 64 + b) * U + u];
    S[gid] = s;
}

// ---------------------------------------------------------------------------
// K1b v3: pack kernel_u into the EXACT per-K-step LDS byte image consumed by
// k_gemm_et, swizzle included. kpack[t] (t=0..15, 32 KB each): position
// (u, slot sc, elem e) holds bf16( ku[t*32 + d*8 + e][u] ), d = sc^((u>>1)&3).
// grid 128 x 256.
__global__ __launch_bounds__(256) void k_prep_kpack(const float* __restrict__ ku,
                                                    unsigned short* __restrict__ kpack) {
    int t = blockIdx.x >> 3;                         // 0..15
    int gid = (blockIdx.x & 7) * 256 + threadIdx.x;  // 0..2047
    int d = gid >> 9;                                // 0..3
    int u = gid & 511;
    float vals[8];
#pragma unroll
    for (int e = 0; e < 8; ++e) vals[e] = ku[(size_t)(t * 32 + d * 8 + e) * U + u];
    int sc = d ^ ((u >> 1) & 3);
    short8 pk;
#pragma unroll
    for (int e = 0; e < 8; ++e) pk[e] = (short)f32_to_bf16(vals[e]);
    *(short8*)&kpack[(size_t)t * 16384 + u * 32 + sc * 8] = pk;
}

// ---------------------------------------------------------------------------
// K1c: Wt[j][k] = bf16( W[k][j] ). grid (48, 64) x 256
__global__ __launch_bounds__(256) void k_prep_wt(const float* __restrict__ kern,
                                                 const float* __restrict__ rk,
                                                 unsigned short* __restrict__ Wt) {
    __shared__ float tile[32][33];
    int k0 = blockIdx.x << 5;
    int j0 = blockIdx.y << 5;
    int c = threadIdx.x & 31, r0 = threadIdx.x >> 5;
#pragma unroll
    for (int p = 0; p < 4; ++p) {
        int r = r0 + p * 8;
        int k = k0 + r;
        float val = (k < 1024) ? kern[k * 2048 + j0 + c]
                               : rk[(k - 1024) * 2048 + j0 + c];
        tile[r][c] = val;
    }
    __syncthreads();
#pragma unroll
    for (int p = 0; p < 4; ++p) {
        int r = r0 + p * 8;
        Wt[(size_t)(j0 + r) * 1536 + k0 + c] = f32_to_bf16(tile[c][r]);
    }
}

// ---------------------------------------------------------------------------
// K2 v6: counted-vmcnt (T3/T4) MFMA GEMM + fused tanh/dot(v) -> et + online
// softmax + ctx partial. 512 thr / 8 waves (2m x 4n); tile M=128 x N=512;
// wave-tile 64x128 (acc 4x8). K=512 in 16 steps of BK=32.
// B: kpack byte image, TRIPLE-buffered (3x32KB), contiguous 1 KB glls.
// A: fp32 reg-staged, XOR-4 swizzled As (0-conflict layout), dbuf.
// Per-wave VMEM FIFO per iter t: [gll(t+1)x4, A(t+1)x2, gll(t+2)x4] ->
// ONE s_waitcnt vmcnt(4) after the MFMAs retires gll(t+1)+A(t+1) while
// gll(t+2) stays in flight ACROSS the raw s_barrier (never vmcnt(0) in
// steady state; m218: counted-vs-drain0 is the whole gain).
// LDS 115 KB -> 1 block/CU, 8 waves; __launch_bounds__(512,2) caps regs
// at 256 so 2 waves/SIMD stay resident. grid 1024 x 512.
__global__ __launch_bounds__(512, 2) void k_gemm_et(const float* __restrict__ ann,
                                                    const unsigned short* __restrict__ kpack,
                                                    const float* __restrict__ S,
                                                    const float* __restrict__ v,
                                                    float* __restrict__ mz,
                                                    float* __restrict__ part) {
    __shared__ unsigned short As[2][128 * 32];   // 16 KB, XOR-4 swizzled
    __shared__ unsigned short Bs[3][512 * 32];   // 96 KB, byte image of kpack[t]
    __shared__ float red[8][64];                 // 2 KB
    __shared__ float elds[128];
    __shared__ float p_lds[128];

    const int tid = threadIdx.x;
    const int wave = tid >> 6;           // 0..7
    const int lane = tid & 63;
    const int lanelo = lane & 15;
    const int quad = lane >> 4;
    const int wr = wave >> 2;            // m-half 0..1
    const int wc = wave & 3;             // n-slice 0..3

    const int mt = blockIdx.x;           // 0..1023
    const int b = mt >> 4;               // 16 m-tiles (128 t's) per batch
    const float* aBase = ann + (size_t)mt * 128 * A;
    const char* kpB = (const char*)kpack;

    f32x4 acc[4][8];
#pragma unroll
    for (int i = 0; i < 4; ++i)
#pragma unroll
        for (int j = 0; j < 8; ++j) acc[i][j] = {0.f, 0.f, 0.f, 0.f};

    // A staging: thread owns row rowA (0..127), 8-float chunk c8A (0..3)
    const int rowA = tid >> 2;
    const int c8A = tid & 3;
    f32x4 pv0, pv1;

    auto load_a = [&](int kk) {
        const float* src = aBase + (size_t)rowA * A + kk + c8A * 8;
        pv0 = *(const f32x4*)src;
        pv1 = *(const f32x4*)(src + 4);
    };
    auto stage_b = [&](int t, int buf) {
        const char* src = kpB + (size_t)t * 32768;
#pragma unroll
        for (int p = 0; p < 4; ++p) {
            int seg = p * 8 + wave;                   // 1 KB segment, 0..31
            __builtin_amdgcn_global_load_lds(
                (const __attribute__((address_space(1))) void*)(src + seg * 1024 + lane * 16),
                (__attribute__((address_space(3))) void*)((char*)&Bs[buf][0] + seg * 1024),
                16, 0, 0);
        }
    };
    auto cvt_store = [&](int buf) {
        short8 pk;
        pk[0] = (short)f32_to_bf16(pv0.x);
        pk[1] = (short)f32_to_bf16(pv0.y);
        pk[2] = (short)f32_to_bf16(pv0.z);
        pk[3] = (short)f32_to_bf16(pv0.w);
        pk[4] = (short)f32_to_bf16(pv1.x);
        pk[5] = (short)f32_to_bf16(pv1.y);
        pk[6] = (short)f32_to_bf16(pv1.z);
        pk[7] = (short)f32_to_bf16(pv1.w);
        *(short8*)&As[buf][rowA * 32 + ((c8A ^ ((rowA >> 1) & 3)) * 8)] = pk;
    };

    // --- prologue: establish invariant (entering iter 0: only gll(1) x4
    // outstanding; As[0], Bs[0] valid) ---
    load_a(0);
    SB();
    stage_b(0, 0);
    SB();
    asm volatile("s_waitcnt vmcnt(4)" ::: "memory");   // A(0) landed
    SB();
    cvt_store(0);
    SB();
    stage_b(1, 1);
    SB();
    asm volatile("s_waitcnt vmcnt(4)" ::: "memory");   // gll(0) landed
    asm volatile("s_waitcnt lgkmcnt(0)" ::: "memory"); // As[0] visible
    __builtin_amdgcn_s_barrier();

#pragma unroll
    for (int t = 0; t < 16; ++t) {
        const int cur = t & 1;
        const int curB = t % 3;

        // --- issue next A (2 loads) then gll(t+2) (4), order pinned ---
        SB();
        if (t < 15) load_a((t + 1) * 32);
        SB();
        if (t < 14) stage_b(t + 2, (t + 2) % 3);
        SB();

        // --- frags from LDS ---
        short8 af[4];
#pragma unroll
        for (int mi = 0; mi < 4; ++mi) {
            int row = wr * 64 + mi * 16 + lanelo;
            af[mi] = *(const short8*)&As[cur][row * 32 + ((quad ^ ((row >> 1) & 3)) * 8)];
        }
        short8 bfr[8];
#pragma unroll
        for (int ni = 0; ni < 8; ++ni) {
            int rowb = wc * 128 + ni * 16 + lanelo;
            bfr[ni] = *(const short8*)&Bs[curB][rowb * 32 + ((quad ^ ((rowb >> 1) & 3)) * 8)];
        }
        asm volatile("s_waitcnt lgkmcnt(0)" ::: "memory");
        SB();   // rule #18: keep MFMAs below the lgkm wait

        __builtin_amdgcn_s_setprio(1);
#pragma unroll
        for (int mi = 0; mi < 4; ++mi)
#pragma unroll
            for (int ni = 0; ni < 8; ++ni)
                acc[mi][ni] = __builtin_amdgcn_mfma_f32_16x16x32_bf16(
                    af[mi], bfr[ni], acc[mi][ni], 0, 0, 0);
        __builtin_amdgcn_s_setprio(0);
        SB();

        if (t < 15) {
            // retire gll(t+1) (Bs[(t+1)%3] ready) + A(t+1); keep gll(t+2)
            // in flight across the barrier.
            if (t == 14) { asm volatile("s_waitcnt vmcnt(0)" ::: "memory"); }
            else         { asm volatile("s_waitcnt vmcnt(4)" ::: "memory"); }
            SB();
            cvt_store((t + 1) & 1);
        }
        asm volatile("s_waitcnt lgkmcnt(0)" ::: "memory");
        __builtin_amdgcn_s_barrier();
    }

    // --- et epilogue. C/D: col(n)=lane&15, row(m)=quad*4+r (m89/m91). ---
    float rows[16];
#pragma unroll
    for (int i = 0; i < 16; ++i) rows[i] = 0.f;
#pragma unroll
    for (int ni = 0; ni < 8; ++ni) {
        int u = wc * 128 + ni * 16 + lanelo;
        float sv = S[b * U + u];
        float vv = v[u];
#pragma unroll
        for (int mi = 0; mi < 4; ++mi)
#pragma unroll
            for (int r = 0; r < 4; ++r)
                rows[mi * 4 + r] += fast_tanh(acc[mi][ni][r] + sv) * vv;
    }
#pragma unroll
    for (int i = 0; i < 16; ++i) {
        rows[i] += __shfl_xor(rows[i], 1);
        rows[i] += __shfl_xor(rows[i], 2);
        rows[i] += __shfl_xor(rows[i], 4);
        rows[i] += __shfl_xor(rows[i], 8);
    }
    if (lanelo == 0) {
#pragma unroll
        for (int mi = 0; mi < 4; ++mi)
#pragma unroll
            for (int r = 0; r < 4; ++r)
                red[wave][mi * 16 + quad * 4 + r] = rows[mi * 4 + r];
    }
    __syncthreads();

    // combine the 4 n-waves per m-half
    if (tid < 128) {
        int wrr = tid >> 6;
        int m = tid & 63;
        elds[tid] = red[wrr * 4 + 0][m] + red[wrr * 4 + 1][m] +
                    red[wrr * 4 + 2][m] + red[wrr * 4 + 3][m];
    }
    __syncthreads();

    // block-local softmax over 128 et values (one wave handles 2 each)
    if (tid < 64) {
        float e0 = elds[tid];
        float e1 = elds[tid + 64];
        float m = fmaxf(e0, e1);
#pragma unroll
        for (int o = 1; o < 64; o <<= 1) m = fmaxf(m, __shfl_xor(m, o));
        float p0 = exp2f((e0 - m) * 1.4426950408889634f);
        float p1 = exp2f((e1 - m) * 1.4426950408889634f);
        float z = p0 + p1;
#pragma unroll
        for (int o = 1; o < 64; o <<= 1) z += __shfl_xor(z, o);
        p_lds[tid] = p0;
        p_lds[tid + 64] = p1;
        if (tid == 0) { mz[mt * 2] = m; mz[mt * 2 + 1] = z; }
    }
    __syncthreads();

    // ctx partial: ctxp[a] = sum_t p[t] * ann[t][a] over this block's own
    // 128x512 fp32 tile (L2/L3-warm). As LDS reused as 4x512 f32 buffer.
    float* cbuf = (float*)&As[0][0];
    {
        int tg = tid >> 7;                  // 0..3
        int a4 = (tid & 127) << 2;          // 0,4,...,508
        f32x4 cacc = {0.f, 0.f, 0.f, 0.f};
#pragma unroll 4
        for (int t2 = tg; t2 < 128; t2 += 4) {
            float w = p_lds[t2];
            f32x4 rv = *(const f32x4*)(aBase + (size_t)t2 * A + a4);
            cacc.x += w * rv.x;
            cacc.y += w * rv.y;
            cacc.z += w * rv.z;
            cacc.w += w * rv.w;
        }
        *(f32x4*)&cbuf[tg * 512 + a4] = cacc;
    }
    __syncthreads();
    {
        int a = tid;
        float s = cbuf[a] + cbuf[512 + a] + cbuf[1024 + a] + cbuf[1536 + a];
        part[(size_t)mt * 512 + a] = s;
    }
}

// ---------------------------------------------------------------------------
// K5 v4: merge 16 per-block online-softmax context partials per batch with
// rescaling, then build xb = bf16([inputs | ctx | h]). grid 64 x 256.
__global__ __launch_bounds__(256) void k_ctx_merge_xb(const float* __restrict__ part,
                                                      const float* __restrict__ mz,
                                                      const float* __restrict__ inputs,
                                                      const float* __restrict__ h,
                                                      unsigned short* __restrict__ xb) {
    int b = blockIdx.x;
    int tid = threadIdx.x;
    __shared__ float wsh[16];
    __shared__ float sinvZ;
    if (tid < 16) {
        float m_i = mz[(b * 16 + tid) * 2];
        float z_i = mz[(b * 16 + tid) * 2 + 1];
        float M = m_i;
#pragma unroll
        for (int o = 1; o < 16; o <<= 1) M = fmaxf(M, __shfl_xor(M, o));
        float w = exp2f((m_i - M) * 1.4426950408889634f);
        float wz = w * z_i;
#pragma unroll
        for (int o = 1; o < 16; o <<= 1) wz += __shfl_xor(wz, o);
        wsh[tid] = w;
        if (tid == 0) sinvZ = 1.0f / wz;
    }
    __syncthreads();
    float invZ = sinvZ;
    unsigned short* xrow = xb + (size_t)b * 1536;
#pragma unroll
    for (int i = 0; i < 2; ++i) {
        int a = tid + i * 256;
        float s = 0.f;
#pragma unroll
        for (int c2 = 0; c2 < 16; ++c2)
            s += wsh[c2] * part[((size_t)b * 16 + c2) * 512 + a];
        xrow[512 + a] = f32_to_bf16(s * invZ);
        xrow[a] = f32_to_bf16(inputs[b * 512 + a]);
        xrow[1024 + a] = f32_to_bf16(h[b * 512 + a]);
    }
}

// ---------------------------------------------------------------------------
// K6a: z-GEMM, split-K MFMA. grid 256 x 256.
__global__ __launch_bounds__(256) void k_zgemm(const unsigned short* __restrict__ xb,
                                               const unsigned short* __restrict__ Wt,
                                               float* __restrict__ zpart) {
    const int kc = blockIdx.x & 7;
    const int nt = blockIdx.x >> 3;
    const int wave = threadIdx.x >> 6;
    const int lane = threadIdx.x & 63;
    const int lanelo = lane & 15;
    const int quad = lane >> 4;

    const int n = nt * 64 + wave * 16 + lanelo;
    const unsigned short* bp = Wt + (size_t)n * 1536 + kc * 192 + quad * 8;
    const unsigned short* ap = xb + (size_t)lanelo * 1536 + kc * 192 + quad * 8;

    f32x4 acc[4];
#pragma unroll
    for (int i = 0; i < 4; ++i) acc[i] = {0.f, 0.f, 0.f, 0.f};

#pragma unroll
    for (int ks = 0; ks < 6; ++ks) {
        short8 bfrag = *(const short8*)(bp + ks * 32);
#pragma unroll
        for (int mi = 0; mi < 4; ++mi) {
            short8 afrag = *(const short8*)(ap + (size_t)mi * 16 * 1536 + ks * 32);
            acc[mi] = __builtin_amdgcn_mfma_f32_16x16x32_bf16(afrag, bfrag, acc[mi], 0, 0, 0);
        }
    }

    float* p = zpart + (size_t)kc * 64 * 2048;
#pragma unroll
    for (int mi = 0; mi < 4; ++mi)
#pragma unroll
        for (int r = 0; r < 4; ++r) {
            int m = mi * 16 + quad * 4 + r;
            p[(size_t)m * 2048 + n] = acc[mi][r];
        }
}

// ---------------------------------------------------------------------------
// K6b: combine partials + bias -> gates -> h_new. grid 128 x 256
__global__ __launch_bounds__(256) void k_gates(const float* __restrict__ zpart,
                                               const float* __restrict__ bias,
                                               const float* __restrict__ c,
                                               float* __restrict__ hnew) {
    int gid = blockIdx.x * 256 + threadIdx.x;
    int b = gid >> 9;
    int u = gid & 511;
    float z[4];
#pragma unroll
    for (int g = 0; g < 4; ++g) {
        int j = (g << 9) + u;
        float s = bias[j];
#pragma unroll
        for (int kc = 0; kc < 8; ++kc)
            s += zpart[((size_t)kc * 64 + b) * 2048 + j];
        z[g] = s;
    }
    float ig = hard_sigmoid(z[0]);
    float fg = hard_sigmoid(z[1]);
    float cn = fg * c[b * 512 + u] + ig * fast_tanh(z[2]);
    float og = hard_sigmoid(z[3]);
    hnew[b * 512 + u] = og * fast_tanh(cn);
}

// ---------------------------------------------------------------------------
extern "C" void kernel_launch(void* const* d_in, const int* in_sizes, int n_in,
                              void* d_out, int out_size, void* d_ws, size_t ws_size,
                              hipStream_t stream) {
    const float* inputs = (const float*)d_in[0];
    const float* h      = (const float*)d_in[1];
    const float* c      = (const float*)d_in[2];
    const float* ann    = (const float*)d_in[3];
    const float* kern   = (const float*)d_in[4];
    const float* rk     = (const float*)d_in[5];
    const float* bias   = (const float*)d_in[6];
    const float* ku     = (const float*)d_in[7];
    const float* kw     = (const float*)d_in[8];
    const float* kv     = (const float*)d_in[9];

    // ws layout (bytes):
    //   S      @ 0         131072
    //   kpack  @ 131072    524288
    //   mz     @ 655360    8192      (1024 x {m,Z})
    //   part   @ 663552    2097152   (1024 x 512 ctx partials)
    //   Sp     @ 2760704   524288
    //   xb     @ 3284992   196608
    //   Wt     @ 3481600   6291456
    //   zpart  @ 9773056   4194304
    char* ws = (char*)d_ws;
    float*          S     = (float*)(ws + 0);
    unsigned short* kpack = (unsigned short*)(ws + 131072);
    float*          mz    = (float*)(ws + 655360);
    float*          part  = (float*)(ws + 663552);
    float*          Sp    = (float*)(ws + 2760704);
    unsigned short* xb    = (unsigned short*)(ws + 3284992);
    unsigned short* Wt    = (unsigned short*)(ws + 3481600);
    float*          zpart = (float*)(ws + 9773056);
    float*          hnew  = (float*)d_out;

    k_prep_wt<<<dim3(48, 64), 256, 0, stream>>>(kern, rk, Wt);
    k_prep_kpack<<<128, 256, 0, stream>>>(ku, kpack);
    k_prep_s<<<256, 256, 0, stream>>>(h, kw, Sp);
    k_s_reduce<<<128, 256, 0, stream>>>(Sp, bias, S);
    k_gemm_et<<<1024, 512, 0, stream>>>(ann, kpack, S, kv, mz, part);
    k_ctx_merge_xb<<<64, 256, 0, stream>>>(part, mz, inputs, h, xb);
    k_zgemm<<<256, 256, 0, stream>>>(xb, Wt, zpart);
    k_gates<<<128, 256, 0, stream>>>(zpart, bias, c, hnew);
}